// Round 2
// baseline (554.147 us; speedup 1.0000x reference)
//
#include <hip/hip_runtime.h>

#define N_NODES 50000
#define N_EDGES 1600000
#define IN_DIM  256
#define OUT_D   128   // N_HEADS * OUT_DIM
#define NEG_SLOPE 0.2f

typedef unsigned short ushort_t;
typedef short bf16x8 __attribute__((ext_vector_type(8)));
typedef float f32x4 __attribute__((ext_vector_type(4)));

__device__ __forceinline__ float bf2f(ushort_t v) {
    return __uint_as_float(((unsigned)v) << 16);
}
__device__ __forceinline__ ushort_t f2bf(float f) {
    unsigned u = __float_as_uint(f);
    u = (u + 0x7FFF + ((u >> 16) & 1)) >> 16;   // RNE
    return (ushort_t)u;
}

// ---------------------------------------------------------------------------
// K0: va[k][slot] = sum_d W[k, h*32+d] * a[d (src) or 32+d (dst), h]
//     slot = h for src, 4+h for dst.  All fp32.
__global__ __launch_bounds__(256) void va_kernel(const float* __restrict__ W,
                                                 const float* __restrict__ a,
                                                 float* __restrict__ vab) {
    int k = threadIdx.x;  // one k per thread
    for (int h = 0; h < 4; ++h) {
        float s0 = 0.f, s1 = 0.f;
        for (int d = 0; d < 32; ++d) {
            float w = W[k * OUT_D + h * 32 + d];
            s0 += w * a[d * 4 + h];
            s1 += w * a[(32 + d) * 4 + h];
        }
        vab[k * 8 + h]     = s0;
        vab[k * 8 + 4 + h] = s1;
    }
}

// ---------------------------------------------------------------------------
// K1: h_prime = bf16(h) @ bf16(W) via MFMA 16x16x32, output bf16.
//     128 rows/block; W transposed->bf16 in LDS with 16B-chunk XOR swizzle.
__global__ __launch_bounds__(256) void gemm_kernel(const float* __restrict__ h,
                                                   const float* __restrict__ W,
                                                   ushort_t* __restrict__ hp) {
    __shared__ ushort_t sW[32768];  // 64 KB: Wt[n][k] bf16, swizzled
    int t = threadIdx.x;
    for (int i = t; i < 32768; i += 256) {
        int k = i >> 7, n = i & 127;           // W[k][n], coalesced global read
        int byte_in_row = 2 * k;
        int sw = ((byte_in_row & ~15) ^ ((n & 7) << 4)) | (byte_in_row & 15);
        sW[(n << 8) + (sw >> 1)] = f2bf(W[i]);
    }
    __syncthreads();

    int wave = t >> 6, lane = t & 63;
    int l15 = lane & 15, quad = lane >> 4;
    int rowbase = blockIdx.x * 128 + wave * 16;   // row tiles: rowbase, rowbase+64

    f32x4 acc[2][8] = {};
#pragma unroll
    for (int ks = 0; ks < 8; ++ks) {
        bf16x8 af[2];
#pragma unroll
        for (int rt = 0; rt < 2; ++rt) {
            int arow = rowbase + rt * 64 + l15;
            if (arow >= N_NODES) arow = N_NODES - 1;  // clamp; stores guarded
            const float* ap = h + (size_t)arow * IN_DIM + quad * 8 + ks * 32;
            f32x4 lo = *(const f32x4*)ap;
            f32x4 hi = *(const f32x4*)(ap + 4);
#pragma unroll
            for (int j = 0; j < 4; ++j) {
                af[rt][j]     = (short)f2bf(lo[j]);
                af[rt][4 + j] = (short)f2bf(hi[j]);
            }
        }
        int koff = ks * 64 + quad * 16;  // byte offset inside Wt row
#pragma unroll
        for (int tn = 0; tn < 8; ++tn) {
            int n = tn * 16 + l15;
            int swz = koff ^ ((n & 7) << 4);
            bf16x8 bfr = *(const bf16x8*)((const char*)sW + n * 512 + swz);
            acc[0][tn] = __builtin_amdgcn_mfma_f32_16x16x32_bf16(af[0], bfr, acc[0][tn], 0, 0, 0);
            acc[1][tn] = __builtin_amdgcn_mfma_f32_16x16x32_bf16(af[1], bfr, acc[1][tn], 0, 0, 0);
        }
    }
#pragma unroll
    for (int rt = 0; rt < 2; ++rt)
#pragma unroll
        for (int tn = 0; tn < 8; ++tn) {
            int col = tn * 16 + l15;
#pragma unroll
            for (int r = 0; r < 4; ++r) {
                int row = rowbase + rt * 64 + quad * 4 + r;  // C/D: col=lane&15, row=quad*4+reg
                if (row < N_NODES) hp[(size_t)row * OUT_D + col] = f2bf(acc[rt][tn][r]);
            }
        }
}

// ---------------------------------------------------------------------------
// K2: alpha[n][slot] = sum_k h[n,k]*va[k][slot], fp32 exact.
//     32 lanes per node, h row read once, shuffle-reduce.
__global__ __launch_bounds__(256) void alpha_kernel(const float* __restrict__ h,
                                                    const float* __restrict__ vab,
                                                    float* __restrict__ asrc,
                                                    float* __restrict__ adst) {
    __shared__ float sva[2048];
    int t = threadIdx.x;
    for (int i = t; i < 2048; i += 256) sva[i] = vab[i];
    __syncthreads();
    int node = blockIdx.x * 8 + (t >> 5);
    int l32 = t & 31;
    if (node >= N_NODES) return;
    const float* hr = h + (size_t)node * IN_DIM + l32 * 8;
    f32x4 lo = *(const f32x4*)hr;
    f32x4 hi = *(const f32x4*)(hr + 4);
    float p[8] = {};
    int k0 = l32 * 8;
#pragma unroll
    for (int j = 0; j < 8; ++j) {
        float hv = (j < 4) ? lo[j] : hi[j - 4];
        const float* vr = &sva[(k0 + j) * 8];
#pragma unroll
        for (int s = 0; s < 8; ++s) p[s] += hv * vr[s];
    }
#pragma unroll
    for (int s = 0; s < 8; ++s) {
#pragma unroll
        for (int o = 16; o > 0; o >>= 1) p[s] += __shfl_xor(p[s], o, 32);
    }
    if (l32 < 4)              asrc[node * 4 + l32] = p[l32];
    else if (l32 < 8)         adst[node * 4 + (l32 - 4)] = p[l32];
}

// ---------------------------------------------------------------------------
// K3: in-degree histogram
__global__ __launch_bounds__(256) void hist_kernel(const int* __restrict__ dst,
                                                   int* __restrict__ deg) {
    int e = blockIdx.x * 256 + threadIdx.x;
    if (e < N_EDGES) atomicAdd(&deg[dst[e]], 1);
}

// ---------------------------------------------------------------------------
// K4: single-block exclusive scan over 50000 degrees -> off[], cursor[]
__global__ __launch_bounds__(1024) void scan_kernel(const int* __restrict__ deg,
                                                    int* __restrict__ off,
                                                    int* __restrict__ cursor) {
    __shared__ int s[1024];
    const int n = N_NODES;
    const int C = (n + 1023) / 1024;  // 49
    int t = threadIdx.x;
    int lo = t * C, hi = min(lo + C, n);
    int sum = 0;
    for (int i = lo; i < hi; ++i) sum += deg[i];
    s[t] = sum;
    __syncthreads();
    for (int d = 1; d < 1024; d <<= 1) {
        int v = (t >= d) ? s[t - d] : 0;
        __syncthreads();
        s[t] += v;
        __syncthreads();
    }
    int base = (t == 0) ? 0 : s[t - 1];
    for (int i = lo; i < hi; ++i) {
        off[i] = base; cursor[i] = base; base += deg[i];
    }
    if (t == 1023) off[n] = s[1023];
}

// ---------------------------------------------------------------------------
// K5: scatter edges into CSR (by dst), payload = src id
__global__ __launch_bounds__(256) void scatter_kernel(const int* __restrict__ src,
                                                      const int* __restrict__ dst,
                                                      int* __restrict__ cursor,
                                                      int* __restrict__ csr) {
    int e = blockIdx.x * 256 + threadIdx.x;
    if (e < N_EDGES) {
        int d = dst[e];
        int p = atomicAdd(&cursor[d], 1);
        csr[p] = src[e];
    }
}

// ---------------------------------------------------------------------------
// K6: per-dst-node online softmax + aggregation. 1 block / node, 128 threads.
#define CH 192
__global__ __launch_bounds__(128) void agg_kernel(const int* __restrict__ off,
                                                  const int* __restrict__ csr,
                                                  const float* __restrict__ asrc,
                                                  const float* __restrict__ adst,
                                                  const ushort_t* __restrict__ hp,
                                                  float* __restrict__ out) {
    int d = blockIdx.x;
    int t = threadIdx.x;
    int head = t >> 5, lane31 = t & 31;
    int s0 = off[d], s1 = off[d + 1];

    __shared__ int   s_src[CH];
    __shared__ float s_att[CH * 4];
    __shared__ float s_m[4], s_scale[4];

    float m_run = -__builtin_inff();
    float sum_run = 0.f, acc = 0.f;

    for (int base = s0; base < s1; base += CH) {
        int n = min(CH, s1 - base);
        for (int i = t; i < n; i += 128) s_src[i] = csr[base + i];
        __syncthreads();
        // att = leaky_relu(alpha_src[s] + alpha_dst[d]) per (edge, head), fp32 exact
        for (int idx = t; idx < n * 4; idx += 128) {
            int e = idx >> 2, hh = idx & 3;
            float v = asrc[s_src[e] * 4 + hh] + adst[d * 4 + hh];
            s_att[idx] = v > 0.f ? v : NEG_SLOPE * v;
        }
        __syncthreads();
        // per-head chunk max
        float lm = -__builtin_inff();
        for (int i = lane31; i < n; i += 32) lm = fmaxf(lm, s_att[i * 4 + head]);
        for (int o = 16; o > 0; o >>= 1) lm = fmaxf(lm, __shfl_down(lm, o, 32));
        if (lane31 == 0) {
            float nm = fmaxf(m_run, lm);
            s_m[head] = nm;
            s_scale[head] = __expf(m_run - nm);  // exp(-inf)=0 on first chunk
        }
        __syncthreads();
        float sc = s_scale[head];
        acc *= sc; sum_run *= sc; m_run = s_m[head];
        for (int idx = t; idx < n * 4; idx += 128)
            s_att[idx] = __expf(s_att[idx] - s_m[idx & 3]);
        __syncthreads();
        // accumulate: thread t owns output column t (= head*32 + dim)
        for (int e = 0; e < n; ++e) {
            float w = s_att[(e << 2) + head];
            sum_run += w;
            acc += w * bf2f(hp[(size_t)s_src[e] * OUT_D + t]);
        }
        __syncthreads();
    }
    out[(size_t)d * OUT_D + t] = (sum_run > 0.f) ? acc / sum_run : 0.f;
}

// ---------------------------------------------------------------------------
extern "C" void kernel_launch(void* const* d_in, const int* in_sizes, int n_in,
                              void* d_out, int out_size, void* d_ws, size_t ws_size,
                              hipStream_t stream) {
    const float* h   = (const float*)d_in[0];
    const int*   adj = (const int*)d_in[1];
    const float* W   = (const float*)d_in[2];
    const float* a   = (const float*)d_in[3];
    float*       out = (float*)d_out;

    const int* src = adj;
    const int* dst = adj + N_EDGES;

    char* ws = (char*)d_ws;
    size_t o = 0;
    auto alloc = [&](size_t bytes) -> void* {
        void* p = ws + o;
        o = (o + bytes + 255) & ~(size_t)255;
        return p;
    };
    ushort_t* hp     = (ushort_t*)alloc((size_t)N_NODES * OUT_D * 2);  // 12.8 MB bf16
    float*    vab    = (float*)alloc(2048 * 4);
    float*    asrc   = (float*)alloc((size_t)N_NODES * 4 * 4);
    float*    adstp  = (float*)alloc((size_t)N_NODES * 4 * 4);
    int*      deg    = (int*)alloc((size_t)N_NODES * 4);
    int*      off    = (int*)alloc((size_t)(N_NODES + 1) * 4);
    int*      cursor = (int*)alloc((size_t)N_NODES * 4);
    int*      csr    = (int*)alloc((size_t)N_EDGES * 4);               // 6.4 MB

    hipMemsetAsync(deg, 0, (size_t)N_NODES * 4, stream);

    va_kernel<<<1, 256, 0, stream>>>(W, a, vab);
    gemm_kernel<<<(N_NODES + 127) / 128, 256, 0, stream>>>(h, W, hp);
    alpha_kernel<<<(N_NODES + 7) / 8, 256, 0, stream>>>(h, vab, asrc, adstp);
    hist_kernel<<<N_EDGES / 256, 256, 0, stream>>>(dst, deg);
    scan_kernel<<<1, 1024, 0, stream>>>(deg, off, cursor);
    scatter_kernel<<<N_EDGES / 256, 256, 0, stream>>>(src, dst, cursor, csr);
    agg_kernel<<<N_NODES, 128, 0, stream>>>(off, csr, asrc, adstp, hp, out);
}

// Round 3
// 510.093 us; speedup vs baseline: 1.0864x; 1.0864x over previous
//
#include <hip/hip_runtime.h>

#define N_NODES 50000
#define N_EDGES 1600000
#define IN_DIM  256
#define OUT_D   128   // N_HEADS * OUT_DIM
#define NEG_SLOPE 0.2f
#define PART 6250     // N_NODES / 8 (dst-partition per XCD)

typedef unsigned short ushort_t;
typedef short bf16x8 __attribute__((ext_vector_type(8)));
typedef float f32x4 __attribute__((ext_vector_type(4)));

__device__ __forceinline__ float bf2f(ushort_t v) {
    return __uint_as_float(((unsigned)v) << 16);
}
__device__ __forceinline__ ushort_t f2bf(float f) {
    unsigned u = __float_as_uint(f);
    u = (u + 0x7FFF + ((u >> 16) & 1)) >> 16;   // RNE
    return (ushort_t)u;
}

// ---------------------------------------------------------------------------
// K0: va[k][slot] = sum_d W[k, h*32+d] * a[d (src) or 32+d (dst), h]
__global__ __launch_bounds__(256) void va_kernel(const float* __restrict__ W,
                                                 const float* __restrict__ a,
                                                 float* __restrict__ vab) {
    int k = threadIdx.x;
    for (int h = 0; h < 4; ++h) {
        float s0 = 0.f, s1 = 0.f;
        for (int d = 0; d < 32; ++d) {
            float w = W[k * OUT_D + h * 32 + d];
            s0 += w * a[d * 4 + h];
            s1 += w * a[(32 + d) * 4 + h];
        }
        vab[k * 8 + h]     = s0;
        vab[k * 8 + 4 + h] = s1;
    }
}

// ---------------------------------------------------------------------------
// K1: h_prime = bf16(h) @ bf16(W) via MFMA 16x16x32, output bf16.
__global__ __launch_bounds__(256) void gemm_kernel(const float* __restrict__ h,
                                                   const float* __restrict__ W,
                                                   ushort_t* __restrict__ hp) {
    __shared__ ushort_t sW[32768];  // 64 KB: Wt[n][k] bf16, 16B-chunk XOR swizzle
    int t = threadIdx.x;
    for (int i = t; i < 32768; i += 256) {
        int k = i >> 7, n = i & 127;
        int byte_in_row = 2 * k;
        int sw = ((byte_in_row & ~15) ^ ((n & 7) << 4)) | (byte_in_row & 15);
        sW[(n << 8) + (sw >> 1)] = f2bf(W[i]);
    }
    __syncthreads();

    int wave = t >> 6, lane = t & 63;
    int l15 = lane & 15, quad = lane >> 4;
    int rowbase = blockIdx.x * 128 + wave * 16;

    f32x4 acc[2][8] = {};
#pragma unroll
    for (int ks = 0; ks < 8; ++ks) {
        bf16x8 af[2];
#pragma unroll
        for (int rt = 0; rt < 2; ++rt) {
            int arow = rowbase + rt * 64 + l15;
            if (arow >= N_NODES) arow = N_NODES - 1;
            const float* ap = h + (size_t)arow * IN_DIM + quad * 8 + ks * 32;
            f32x4 lo = *(const f32x4*)ap;
            f32x4 hi = *(const f32x4*)(ap + 4);
#pragma unroll
            for (int j = 0; j < 4; ++j) {
                af[rt][j]     = (short)f2bf(lo[j]);
                af[rt][4 + j] = (short)f2bf(hi[j]);
            }
        }
        int koff = ks * 64 + quad * 16;
#pragma unroll
        for (int tn = 0; tn < 8; ++tn) {
            int n = tn * 16 + l15;
            int swz = koff ^ ((n & 7) << 4);
            bf16x8 bfr = *(const bf16x8*)((const char*)sW + n * 512 + swz);
            acc[0][tn] = __builtin_amdgcn_mfma_f32_16x16x32_bf16(af[0], bfr, acc[0][tn], 0, 0, 0);
            acc[1][tn] = __builtin_amdgcn_mfma_f32_16x16x32_bf16(af[1], bfr, acc[1][tn], 0, 0, 0);
        }
    }
#pragma unroll
    for (int rt = 0; rt < 2; ++rt)
#pragma unroll
        for (int tn = 0; tn < 8; ++tn) {
            int col = tn * 16 + l15;
#pragma unroll
            for (int r = 0; r < 4; ++r) {
                int row = rowbase + rt * 64 + quad * 4 + r;
                if (row < N_NODES) hp[(size_t)row * OUT_D + col] = f2bf(acc[rt][tn][r]);
            }
        }
}

// ---------------------------------------------------------------------------
// K2: alpha[n][slot] = sum_k h[n,k]*va[k][slot], fp32 exact.
__global__ __launch_bounds__(256) void alpha_kernel(const float* __restrict__ h,
                                                    const float* __restrict__ vab,
                                                    float* __restrict__ asrc,
                                                    float* __restrict__ adst) {
    __shared__ float sva[2048];
    int t = threadIdx.x;
    for (int i = t; i < 2048; i += 256) sva[i] = vab[i];
    __syncthreads();
    int node = blockIdx.x * 8 + (t >> 5);
    int l32 = t & 31;
    if (node >= N_NODES) return;
    const float* hr = h + (size_t)node * IN_DIM + l32 * 8;
    f32x4 lo = *(const f32x4*)hr;
    f32x4 hi = *(const f32x4*)(hr + 4);
    float p[8] = {};
    int k0 = l32 * 8;
#pragma unroll
    for (int j = 0; j < 8; ++j) {
        float hv = (j < 4) ? lo[j] : hi[j - 4];
        const float* vr = &sva[(k0 + j) * 8];
#pragma unroll
        for (int s = 0; s < 8; ++s) p[s] += hv * vr[s];
    }
#pragma unroll
    for (int s = 0; s < 8; ++s) {
#pragma unroll
        for (int o = 16; o > 0; o >>= 1) p[s] += __shfl_xor(p[s], o, 32);
    }
    if (l32 < 4)      asrc[node * 4 + l32] = p[l32];
    else if (l32 < 8) adst[node * 4 + (l32 - 4)] = p[l32];
}

// ---------------------------------------------------------------------------
// K3: in-degree histogram, XCD-partitioned by dst range (blockIdx%8 ~ XCD).
//     Each block scans a 2048-edge chunk, commits only its partition's edges.
__global__ __launch_bounds__(256) void hist_kernel(const int* __restrict__ dst,
                                                   int* __restrict__ deg) {
    int part = blockIdx.x & 7;
    int lo = part * PART;
    int e0 = (blockIdx.x >> 3) * 2048 + threadIdx.x * 8;
    int d[8];
    if (e0 + 8 <= N_EDGES) {
        int4 a = *(const int4*)(dst + e0);
        int4 b = *(const int4*)(dst + e0 + 4);
        d[0]=a.x; d[1]=a.y; d[2]=a.z; d[3]=a.w;
        d[4]=b.x; d[5]=b.y; d[6]=b.z; d[7]=b.w;
    } else {
#pragma unroll
        for (int j = 0; j < 8; ++j) d[j] = (e0 + j < N_EDGES) ? dst[e0 + j] : -1;
    }
#pragma unroll
    for (int j = 0; j < 8; ++j) {
        unsigned r = (unsigned)(d[j] - lo);
        if (r < (unsigned)PART) atomicAdd(&deg[lo + (int)r], 1);
    }
}

// ---------------------------------------------------------------------------
// K4: single-block exclusive scan over 50000 degrees -> off[], cursor[]
__global__ __launch_bounds__(1024) void scan_kernel(const int* __restrict__ deg,
                                                    int* __restrict__ off,
                                                    int* __restrict__ cursor) {
    __shared__ int s[1024];
    const int n = N_NODES;
    const int C = (n + 1023) / 1024;  // 49
    int t = threadIdx.x;
    int lo = t * C, hi = min(lo + C, n);
    int sum = 0;
    for (int i = lo; i < hi; ++i) sum += deg[i];
    s[t] = sum;
    __syncthreads();
    for (int d = 1; d < 1024; d <<= 1) {
        int v = (t >= d) ? s[t - d] : 0;
        __syncthreads();
        s[t] += v;
        __syncthreads();
    }
    int base = (t == 0) ? 0 : s[t - 1];
    for (int i = lo; i < hi; ++i) {
        off[i] = base; cursor[i] = base; base += deg[i];
    }
    if (t == 1023) off[n] = s[1023];
}

// ---------------------------------------------------------------------------
// K5: scatter edges into CSR, XCD-partitioned by dst range.
//     Partition p's csr bytes are contiguous [off[p*PART], off[(p+1)*PART])
//     and written only by blocks with blockIdx%8==p -> lines complete in one L2.
__global__ __launch_bounds__(256) void scatter_kernel(const int* __restrict__ src,
                                                      const int* __restrict__ dst,
                                                      int* __restrict__ cursor,
                                                      int* __restrict__ csr) {
    int part = blockIdx.x & 7;
    int lo = part * PART;
    int e0 = (blockIdx.x >> 3) * 2048 + threadIdx.x * 8;
    int d[8], s[8];
    if (e0 + 8 <= N_EDGES) {
        int4 a = *(const int4*)(dst + e0);
        int4 b = *(const int4*)(dst + e0 + 4);
        d[0]=a.x; d[1]=a.y; d[2]=a.z; d[3]=a.w;
        d[4]=b.x; d[5]=b.y; d[6]=b.z; d[7]=b.w;
        int4 c = *(const int4*)(src + e0);
        int4 e = *(const int4*)(src + e0 + 4);
        s[0]=c.x; s[1]=c.y; s[2]=c.z; s[3]=c.w;
        s[4]=e.x; s[5]=e.y; s[6]=e.z; s[7]=e.w;
    } else {
#pragma unroll
        for (int j = 0; j < 8; ++j) {
            bool ok = (e0 + j < N_EDGES);
            d[j] = ok ? dst[e0 + j] : -1;
            s[j] = ok ? src[e0 + j] : 0;
        }
    }
#pragma unroll
    for (int j = 0; j < 8; ++j) {
        unsigned r = (unsigned)(d[j] - lo);
        if (r < (unsigned)PART) {
            int p = atomicAdd(&cursor[lo + (int)r], 1);
            csr[p] = s[j];
        }
    }
}

// ---------------------------------------------------------------------------
// K6: per-dst-node online softmax + aggregation. 1 block / node, 128 threads.
//     blockIdx remapped so node d is on XCD d/PART (csr + out locality).
#define CH 192
__global__ __launch_bounds__(128) void agg_kernel(const int* __restrict__ off,
                                                  const int* __restrict__ csr,
                                                  const float* __restrict__ asrc,
                                                  const float* __restrict__ adst,
                                                  const ushort_t* __restrict__ hp,
                                                  float* __restrict__ out) {
    int d = (blockIdx.x & 7) * PART + (blockIdx.x >> 3);
    int t = threadIdx.x;
    int head = t >> 5, lane31 = t & 31;
    int s0 = off[d], s1 = off[d + 1];

    __shared__ int   s_src[CH];
    __shared__ float s_att[CH * 4];
    __shared__ float s_m[4], s_scale[4];

    float m_run = -__builtin_inff();
    float sum_run = 0.f, acc = 0.f;

    for (int base = s0; base < s1; base += CH) {
        int n = min(CH, s1 - base);
        for (int i = t; i < n; i += 128) s_src[i] = csr[base + i];
        __syncthreads();
        for (int idx = t; idx < n * 4; idx += 128) {
            int e = idx >> 2, hh = idx & 3;
            float v = asrc[s_src[e] * 4 + hh] + adst[d * 4 + hh];
            s_att[idx] = v > 0.f ? v : NEG_SLOPE * v;
        }
        __syncthreads();
        float lm = -__builtin_inff();
        for (int i = lane31; i < n; i += 32) lm = fmaxf(lm, s_att[i * 4 + head]);
        for (int o = 16; o > 0; o >>= 1) lm = fmaxf(lm, __shfl_down(lm, o, 32));
        if (lane31 == 0) {
            float nm = fmaxf(m_run, lm);
            s_m[head] = nm;
            s_scale[head] = __expf(m_run - nm);  // exp(-inf)=0 on first chunk
        }
        __syncthreads();
        float sc = s_scale[head];
        acc *= sc; sum_run *= sc; m_run = s_m[head];
        for (int idx = t; idx < n * 4; idx += 128)
            s_att[idx] = __expf(s_att[idx] - s_m[idx & 3]);
        __syncthreads();
        for (int e = 0; e < n; ++e) {
            float w = s_att[(e << 2) + head];
            sum_run += w;
            acc += w * bf2f(hp[(size_t)s_src[e] * OUT_D + t]);
        }
        __syncthreads();
    }
    out[(size_t)d * OUT_D + t] = (sum_run > 0.f) ? acc / sum_run : 0.f;
}

// ---------------------------------------------------------------------------
extern "C" void kernel_launch(void* const* d_in, const int* in_sizes, int n_in,
                              void* d_out, int out_size, void* d_ws, size_t ws_size,
                              hipStream_t stream) {
    const float* h   = (const float*)d_in[0];
    const int*   adj = (const int*)d_in[1];
    const float* W   = (const float*)d_in[2];
    const float* a   = (const float*)d_in[3];
    float*       out = (float*)d_out;

    const int* src = adj;
    const int* dst = adj + N_EDGES;

    char* ws = (char*)d_ws;
    size_t o = 0;
    auto alloc = [&](size_t bytes) -> void* {
        void* p = ws + o;
        o = (o + bytes + 255) & ~(size_t)255;
        return p;
    };
    ushort_t* hp     = (ushort_t*)alloc((size_t)N_NODES * OUT_D * 2);  // 12.8 MB bf16
    float*    vab    = (float*)alloc(2048 * 4);
    float*    asrc   = (float*)alloc((size_t)N_NODES * 4 * 4);
    float*    adstp  = (float*)alloc((size_t)N_NODES * 4 * 4);
    int*      deg    = (int*)alloc((size_t)N_NODES * 4);
    int*      off    = (int*)alloc((size_t)(N_NODES + 1) * 4);
    int*      cursor = (int*)alloc((size_t)N_NODES * 4);
    int*      csr    = (int*)alloc((size_t)N_EDGES * 4);               // 6.4 MB

    hipMemsetAsync(deg, 0, (size_t)N_NODES * 4, stream);

    const int chunks = (N_EDGES + 2047) / 2048;   // 782

    va_kernel<<<1, 256, 0, stream>>>(W, a, vab);
    gemm_kernel<<<(N_NODES + 127) / 128, 256, 0, stream>>>(h, W, hp);
    alpha_kernel<<<(N_NODES + 7) / 8, 256, 0, stream>>>(h, vab, asrc, adstp);
    hist_kernel<<<chunks * 8, 256, 0, stream>>>(dst, deg);
    scan_kernel<<<1, 1024, 0, stream>>>(deg, off, cursor);
    scatter_kernel<<<chunks * 8, 256, 0, stream>>>(src, dst, cursor, csr);
    agg_kernel<<<N_NODES, 128, 0, stream>>>(off, csr, asrc, adstp, hp, out);
}

// Round 4
// 408.722 us; speedup vs baseline: 1.3558x; 1.2480x over previous
//
#include <hip/hip_runtime.h>

#define N_NODES 50000
#define N_EDGES 1600000
#define IN_DIM  256
#define OUT_D   128   // N_HEADS * OUT_DIM
#define NEG_SLOPE 0.2f
#define PART 6250     // N_NODES / 8 (dst-partition per XCD)
#define SCAN_TILE 1024
#define SCAN_NB ((N_NODES + SCAN_TILE - 1) / SCAN_TILE)   // 49

typedef unsigned short ushort_t;
typedef short bf16x8 __attribute__((ext_vector_type(8)));
typedef float f32x4 __attribute__((ext_vector_type(4)));

__device__ __forceinline__ float bf2f(ushort_t v) {
    return __uint_as_float(((unsigned)v) << 16);
}
__device__ __forceinline__ ushort_t f2bf(float f) {
    unsigned u = __float_as_uint(f);
    u = (u + 0x7FFF + ((u >> 16) & 1)) >> 16;   // RNE
    return (ushort_t)u;
}

// ---------------------------------------------------------------------------
// K0: va[k][slot] = sum_d W[k, h*32+d] * a[d (src) or 32+d (dst), h]
__global__ __launch_bounds__(256) void va_kernel(const float* __restrict__ W,
                                                 const float* __restrict__ a,
                                                 float* __restrict__ vab) {
    int k = threadIdx.x;
    for (int h = 0; h < 4; ++h) {
        float s0 = 0.f, s1 = 0.f;
        for (int d = 0; d < 32; ++d) {
            float w = W[k * OUT_D + h * 32 + d];
            s0 += w * a[d * 4 + h];
            s1 += w * a[(32 + d) * 4 + h];
        }
        vab[k * 8 + h]     = s0;
        vab[k * 8 + 4 + h] = s1;
    }
}

// ---------------------------------------------------------------------------
// K1: h_prime = bf16(h) @ bf16(W) via MFMA 16x16x32, output bf16.
__global__ __launch_bounds__(256) void gemm_kernel(const float* __restrict__ h,
                                                   const float* __restrict__ W,
                                                   ushort_t* __restrict__ hp) {
    __shared__ ushort_t sW[32768];  // 64 KB: Wt[n][k] bf16, 16B-chunk XOR swizzle
    int t = threadIdx.x;
    for (int i = t; i < 32768; i += 256) {
        int k = i >> 7, n = i & 127;
        int byte_in_row = 2 * k;
        int sw = ((byte_in_row & ~15) ^ ((n & 7) << 4)) | (byte_in_row & 15);
        sW[(n << 8) + (sw >> 1)] = f2bf(W[i]);
    }
    __syncthreads();

    int wave = t >> 6, lane = t & 63;
    int l15 = lane & 15, quad = lane >> 4;
    int rowbase = blockIdx.x * 128 + wave * 16;

    f32x4 acc[2][8] = {};
#pragma unroll
    for (int ks = 0; ks < 8; ++ks) {
        bf16x8 af[2];
#pragma unroll
        for (int rt = 0; rt < 2; ++rt) {
            int arow = rowbase + rt * 64 + l15;
            if (arow >= N_NODES) arow = N_NODES - 1;
            const float* ap = h + (size_t)arow * IN_DIM + quad * 8 + ks * 32;
            f32x4 lo = *(const f32x4*)ap;
            f32x4 hi = *(const f32x4*)(ap + 4);
#pragma unroll
            for (int j = 0; j < 4; ++j) {
                af[rt][j]     = (short)f2bf(lo[j]);
                af[rt][4 + j] = (short)f2bf(hi[j]);
            }
        }
        int koff = ks * 64 + quad * 16;
#pragma unroll
        for (int tn = 0; tn < 8; ++tn) {
            int n = tn * 16 + l15;
            int swz = koff ^ ((n & 7) << 4);
            bf16x8 bfr = *(const bf16x8*)((const char*)sW + n * 512 + swz);
            acc[0][tn] = __builtin_amdgcn_mfma_f32_16x16x32_bf16(af[0], bfr, acc[0][tn], 0, 0, 0);
            acc[1][tn] = __builtin_amdgcn_mfma_f32_16x16x32_bf16(af[1], bfr, acc[1][tn], 0, 0, 0);
        }
    }
#pragma unroll
    for (int rt = 0; rt < 2; ++rt)
#pragma unroll
        for (int tn = 0; tn < 8; ++tn) {
            int col = tn * 16 + l15;
#pragma unroll
            for (int r = 0; r < 4; ++r) {
                int row = rowbase + rt * 64 + quad * 4 + r;
                if (row < N_NODES) hp[(size_t)row * OUT_D + col] = f2bf(acc[rt][tn][r]);
            }
        }
}

// ---------------------------------------------------------------------------
// K2: alpha[n][slot] = sum_k h[n,k]*va[k][slot], fp32 exact.
__global__ __launch_bounds__(256) void alpha_kernel(const float* __restrict__ h,
                                                    const float* __restrict__ vab,
                                                    float* __restrict__ asrc,
                                                    float* __restrict__ adst) {
    __shared__ float sva[2048];
    int t = threadIdx.x;
    for (int i = t; i < 2048; i += 256) sva[i] = vab[i];
    __syncthreads();
    int node = blockIdx.x * 8 + (t >> 5);
    int l32 = t & 31;
    if (node >= N_NODES) return;
    const float* hr = h + (size_t)node * IN_DIM + l32 * 8;
    f32x4 lo = *(const f32x4*)hr;
    f32x4 hi = *(const f32x4*)(hr + 4);
    float p[8] = {};
    int k0 = l32 * 8;
#pragma unroll
    for (int j = 0; j < 8; ++j) {
        float hv = (j < 4) ? lo[j] : hi[j - 4];
        const float* vr = &sva[(k0 + j) * 8];
#pragma unroll
        for (int s = 0; s < 8; ++s) p[s] += hv * vr[s];
    }
#pragma unroll
    for (int s = 0; s < 8; ++s) {
#pragma unroll
        for (int o = 16; o > 0; o >>= 1) p[s] += __shfl_xor(p[s], o, 32);
    }
    if (l32 < 4)      asrc[node * 4 + l32] = p[l32];
    else if (l32 < 8) adst[node * 4 + (l32 - 4)] = p[l32];
}

// ---------------------------------------------------------------------------
// K3: in-degree histogram, XCD-partitioned by dst range (blockIdx%8 ~ XCD).
__global__ __launch_bounds__(256) void hist_kernel(const int* __restrict__ dst,
                                                   int* __restrict__ deg) {
    int part = blockIdx.x & 7;
    int lo = part * PART;
    int e0 = (blockIdx.x >> 3) * 2048 + threadIdx.x * 8;
    int d[8];
    if (e0 + 8 <= N_EDGES) {
        int4 a = *(const int4*)(dst + e0);
        int4 b = *(const int4*)(dst + e0 + 4);
        d[0]=a.x; d[1]=a.y; d[2]=a.z; d[3]=a.w;
        d[4]=b.x; d[5]=b.y; d[6]=b.z; d[7]=b.w;
    } else {
#pragma unroll
        for (int j = 0; j < 8; ++j) d[j] = (e0 + j < N_EDGES) ? dst[e0 + j] : -1;
    }
#pragma unroll
    for (int j = 0; j < 8; ++j) {
        unsigned r = (unsigned)(d[j] - lo);
        if (r < (unsigned)PART) atomicAdd(&deg[lo + (int)r], 1);
    }
}

// ---------------------------------------------------------------------------
// K4a: per-block sums of 1024-element tiles (coalesced int4)
__global__ __launch_bounds__(256) void scan_part_kernel(const int* __restrict__ deg,
                                                        int* __restrict__ bsum) {
    int t = threadIdx.x;
    int base = blockIdx.x * SCAN_TILE + t * 4;
    int4 v = {0, 0, 0, 0};
    if (base + 4 <= N_NODES) v = *(const int4*)(deg + base);
    else {
        if (base + 0 < N_NODES) v.x = deg[base + 0];
        if (base + 1 < N_NODES) v.y = deg[base + 1];
        if (base + 2 < N_NODES) v.z = deg[base + 2];
        if (base + 3 < N_NODES) v.w = deg[base + 3];
    }
    int s = v.x + v.y + v.z + v.w;
#pragma unroll
    for (int o = 32; o > 0; o >>= 1) s += __shfl_down(s, o, 64);
    __shared__ int ws[4];
    if ((t & 63) == 0) ws[t >> 6] = s;
    __syncthreads();
    if (t == 0) bsum[blockIdx.x] = ws[0] + ws[1] + ws[2] + ws[3];
}

// K4b: exclusive scan of the 49 block sums (single wave)
__global__ __launch_bounds__(64) void scan_top_kernel(const int* __restrict__ bsum,
                                                      int* __restrict__ bbase) {
    int t = threadIdx.x;
    int v = (t < SCAN_NB) ? bsum[t] : 0;
    int inc = v;
#pragma unroll
    for (int o = 1; o < 64; o <<= 1) {
        int u = __shfl_up(inc, o, 64);
        if (t >= o) inc += u;
    }
    if (t < SCAN_NB) bbase[t] = inc - v;   // exclusive
}

// K4c: in-block exclusive scan + block base -> off[], cursor[] (coalesced int4)
__global__ __launch_bounds__(256) void scan_final_kernel(const int* __restrict__ deg,
                                                         const int* __restrict__ bbase,
                                                         int* __restrict__ off,
                                                         int* __restrict__ cursor) {
    int t = threadIdx.x;
    int base = blockIdx.x * SCAN_TILE + t * 4;
    int4 v = {0, 0, 0, 0};
    if (base + 4 <= N_NODES) v = *(const int4*)(deg + base);
    else {
        if (base + 0 < N_NODES) v.x = deg[base + 0];
        if (base + 1 < N_NODES) v.y = deg[base + 1];
        if (base + 2 < N_NODES) v.z = deg[base + 2];
        if (base + 3 < N_NODES) v.w = deg[base + 3];
    }
    int lsum = v.x + v.y + v.z + v.w;
    int inc = lsum;
    int l64 = t & 63;
#pragma unroll
    for (int o = 1; o < 64; o <<= 1) {
        int u = __shfl_up(inc, o, 64);
        if (l64 >= o) inc += u;
    }
    __shared__ int ws[4];
    if (l64 == 63) ws[t >> 6] = inc;
    __syncthreads();
    int woff = 0;
    for (int w = 0; w < (t >> 6); ++w) woff += ws[w];
    int ex = bbase[blockIdx.x] + woff + inc - lsum;  // exclusive prefix of elem base
    int4 o4;
    o4.x = ex;
    o4.y = ex + v.x;
    o4.z = ex + v.x + v.y;
    o4.w = ex + v.x + v.y + v.z;
    if (base + 4 <= N_NODES) {
        *(int4*)(off + base) = o4;
        *(int4*)(cursor + base) = o4;
    } else {
        if (base + 0 < N_NODES) { off[base + 0] = o4.x; cursor[base + 0] = o4.x; }
        if (base + 1 < N_NODES) { off[base + 1] = o4.y; cursor[base + 1] = o4.y; }
        if (base + 2 < N_NODES) { off[base + 2] = o4.z; cursor[base + 2] = o4.z; }
        if (base + 3 < N_NODES) { off[base + 3] = o4.w; cursor[base + 3] = o4.w; }
    }
    if (blockIdx.x == 0 && t == 0) off[N_NODES] = N_EDGES;
}

// ---------------------------------------------------------------------------
// K5: scatter edges into CSR, XCD-partitioned by dst range.
__global__ __launch_bounds__(256) void scatter_kernel(const int* __restrict__ src,
                                                      const int* __restrict__ dst,
                                                      int* __restrict__ cursor,
                                                      int* __restrict__ csr) {
    int part = blockIdx.x & 7;
    int lo = part * PART;
    int e0 = (blockIdx.x >> 3) * 2048 + threadIdx.x * 8;
    int d[8], s[8];
    if (e0 + 8 <= N_EDGES) {
        int4 a = *(const int4*)(dst + e0);
        int4 b = *(const int4*)(dst + e0 + 4);
        d[0]=a.x; d[1]=a.y; d[2]=a.z; d[3]=a.w;
        d[4]=b.x; d[5]=b.y; d[6]=b.z; d[7]=b.w;
        int4 c = *(const int4*)(src + e0);
        int4 e = *(const int4*)(src + e0 + 4);
        s[0]=c.x; s[1]=c.y; s[2]=c.z; s[3]=c.w;
        s[4]=e.x; s[5]=e.y; s[6]=e.z; s[7]=e.w;
    } else {
#pragma unroll
        for (int j = 0; j < 8; ++j) {
            bool ok = (e0 + j < N_EDGES);
            d[j] = ok ? dst[e0 + j] : -1;
            s[j] = ok ? src[e0 + j] : 0;
        }
    }
#pragma unroll
    for (int j = 0; j < 8; ++j) {
        unsigned r = (unsigned)(d[j] - lo);
        if (r < (unsigned)PART) {
            int p = atomicAdd(&cursor[lo + (int)r], 1);
            csr[p] = s[j];
        }
    }
}

// ---------------------------------------------------------------------------
// K6: per-dst-node online softmax + aggregation. 1 block / node, 128 threads.
#define CH 192
__global__ __launch_bounds__(128) void agg_kernel(const int* __restrict__ off,
                                                  const int* __restrict__ csr,
                                                  const float* __restrict__ asrc,
                                                  const float* __restrict__ adst,
                                                  const ushort_t* __restrict__ hp,
                                                  float* __restrict__ out) {
    int d = (blockIdx.x & 7) * PART + (blockIdx.x >> 3);
    int t = threadIdx.x;
    int head = t >> 5, lane31 = t & 31;
    int s0 = off[d], s1 = off[d + 1];

    __shared__ int   s_src[CH];
    __shared__ float s_att[CH * 4];
    __shared__ float s_m[4], s_scale[4];

    float m_run = -__builtin_inff();
    float sum_run = 0.f, acc = 0.f;

    for (int base = s0; base < s1; base += CH) {
        int n = min(CH, s1 - base);
        for (int i = t; i < n; i += 128) s_src[i] = csr[base + i];
        __syncthreads();
        for (int idx = t; idx < n * 4; idx += 128) {
            int e = idx >> 2, hh = idx & 3;
            float v = asrc[s_src[e] * 4 + hh] + adst[d * 4 + hh];
            s_att[idx] = v > 0.f ? v : NEG_SLOPE * v;
        }
        __syncthreads();
        float lm = -__builtin_inff();
        for (int i = lane31; i < n; i += 32) lm = fmaxf(lm, s_att[i * 4 + head]);
        for (int o = 16; o > 0; o >>= 1) lm = fmaxf(lm, __shfl_down(lm, o, 32));
        if (lane31 == 0) {
            float nm = fmaxf(m_run, lm);
            s_m[head] = nm;
            s_scale[head] = __expf(m_run - nm);  // exp(-inf)=0 on first chunk
        }
        __syncthreads();
        float sc = s_scale[head];
        acc *= sc; sum_run *= sc; m_run = s_m[head];
        for (int idx = t; idx < n * 4; idx += 128)
            s_att[idx] = __expf(s_att[idx] - s_m[idx & 3]);
        __syncthreads();
        for (int e = 0; e < n; ++e) {
            float w = s_att[(e << 2) + head];
            sum_run += w;
            acc += w * bf2f(hp[(size_t)s_src[e] * OUT_D + t]);
        }
        __syncthreads();
    }
    out[(size_t)d * OUT_D + t] = (sum_run > 0.f) ? acc / sum_run : 0.f;
}

// ---------------------------------------------------------------------------
extern "C" void kernel_launch(void* const* d_in, const int* in_sizes, int n_in,
                              void* d_out, int out_size, void* d_ws, size_t ws_size,
                              hipStream_t stream) {
    const float* h   = (const float*)d_in[0];
    const int*   adj = (const int*)d_in[1];
    const float* W   = (const float*)d_in[2];
    const float* a   = (const float*)d_in[3];
    float*       out = (float*)d_out;

    const int* src = adj;
    const int* dst = adj + N_EDGES;

    char* ws = (char*)d_ws;
    size_t o = 0;
    auto alloc = [&](size_t bytes) -> void* {
        void* p = ws + o;
        o = (o + bytes + 255) & ~(size_t)255;
        return p;
    };
    ushort_t* hp     = (ushort_t*)alloc((size_t)N_NODES * OUT_D * 2);  // 12.8 MB bf16
    float*    vab    = (float*)alloc(2048 * 4);
    float*    asrc   = (float*)alloc((size_t)N_NODES * 4 * 4);
    float*    adstp  = (float*)alloc((size_t)N_NODES * 4 * 4);
    int*      deg    = (int*)alloc((size_t)N_NODES * 4);
    int*      off    = (int*)alloc((size_t)(N_NODES + 1) * 4);
    int*      cursor = (int*)alloc((size_t)N_NODES * 4);
    int*      csr    = (int*)alloc((size_t)N_EDGES * 4);               // 6.4 MB
    int*      bsum   = (int*)alloc((size_t)SCAN_NB * 4);
    int*      bbase  = (int*)alloc((size_t)SCAN_NB * 4);

    hipMemsetAsync(deg, 0, (size_t)N_NODES * 4, stream);

    const int chunks = (N_EDGES + 2047) / 2048;   // 782

    va_kernel<<<1, 256, 0, stream>>>(W, a, vab);
    gemm_kernel<<<(N_NODES + 127) / 128, 256, 0, stream>>>(h, W, hp);
    alpha_kernel<<<(N_NODES + 7) / 8, 256, 0, stream>>>(h, vab, asrc, adstp);
    hist_kernel<<<chunks * 8, 256, 0, stream>>>(dst, deg);
    scan_part_kernel<<<SCAN_NB, 256, 0, stream>>>(deg, bsum);
    scan_top_kernel<<<1, 64, 0, stream>>>(bsum, bbase);
    scan_final_kernel<<<SCAN_NB, 256, 0, stream>>>(deg, bbase, off, cursor);
    scatter_kernel<<<chunks * 8, 256, 0, stream>>>(src, dst, cursor, csr);
    agg_kernel<<<N_NODES, 128, 0, stream>>>(off, csr, asrc, adstp, hp, out);
}